// Round 16
// baseline (247.820 us; speedup 1.0000x reference)
//
#include <hip/hip_runtime.h>
#include <hip/hip_bf16.h>
#include <math.h>

// x: (2, 192, 256, 256) f32 ; w_qkv: (192, 576) ; b_qkv: (576,)
// windows: 32x32 = 1024 per batch, 8x8=64 pixels each
// out: (2, 1024, 4, 64, 192) f32
#define NB   2
#define NC   192
#define HW   256
#define NWIN 1024
#define SHW  64
#define NDQ  192
#define WCOL 576

typedef short bf16x8 __attribute__((ext_vector_type(8)));
typedef float f32x4  __attribute__((ext_vector_type(4)));

__device__ inline unsigned int bf16pack(float a, float b) {
  unsigned int ua = __builtin_bit_cast(unsigned int, a);
  ua += 0x7fffu + ((ua >> 16) & 1u);
  unsigned int ub = __builtin_bit_cast(unsigned int, b);
  ub += 0x7fffu + ((ub >> 16) & 1u);
  return (ua >> 16) | (ub & 0xffff0000u);
}

__device__ inline unsigned short bf16r(float a) {
  unsigned int ua = __builtin_bit_cast(unsigned int, a);
  ua += 0x7fffu + ((ua >> 16) & 1u);
  return (unsigned short)(ua >> 16);
}

// ---------------- K0: precompute WvT bf16 [d][c] ----------------
__global__ __launch_bounds__(256) void k0_wvt(const float* __restrict__ w,
                                              unsigned short* __restrict__ wvt) {
  int id = blockIdx.x * 256 + threadIdx.x;   // 192*192 = 36864
  int d = id / NC, c = id - d * NC;
  wvt[d * NC + c] = bf16r(w[c * WCOL + 2 * NDQ + d]);
}

// ---------------- KA: 1 window/block, 256 thr (4 waves); V-GEMM + mean + q/k tail ----------------
// vtmp layout per window (6144 dwords): [((dq*4+pt)*3+dt)*2+rrp][lane];
// dword = pack(bf16(p=pt*16+kg*4+2rrp), bf16(p+1)) at d = dq*48+dt*16+col, lane=kg*16+col.
__global__ __launch_bounds__(256) void kA_vgemm(const float* __restrict__ x,
                                                const unsigned short* __restrict__ wvt,
                                                const float* __restrict__ w,
                                                const float* __restrict__ bias,
                                                unsigned int* __restrict__ vtmp,
                                                float* __restrict__ qw,
                                                float* __restrict__ kwT) {
  int b = blockIdx.y, m = blockIdx.x;   // m in [0,1024)
  int wh = m >> 5, ww = m & 31;
  int t = threadIdx.x;

  __shared__ unsigned short Xs[4096];   // 8 KB: 64 p * 128B (swizzled, half-holes)
  __shared__ float part[32][17];        // conflict-light partials
  __shared__ float xmLds[NC];           // window mean (f32)

  int L = t & 63, dq = t >> 6;          // wave = d-quarter
  int col = L & 15, kg = L >> 4;

  f32x4 acc[4][3];
#pragma unroll
  for (int dt = 0; dt < 3; ++dt) {
    float bv = bias[2 * NDQ + dq * 48 + dt * 16 + col];
    f32x4 bi = {bv, bv, bv, bv};
#pragma unroll
    for (int pt = 0; pt < 4; ++pt) acc[pt][dt] = bi;
  }

  int cp = t & 15, gi = t >> 4;         // gi 0..15 = pixel quad
  int r = gi >> 1, c4 = gi & 1;
  int pS = r * 8 + c4 * 4;
  const float* xb = x + (size_t)(b * NC) * (HW * HW) + (size_t)(wh * 8 + r) * HW + ww * 8 + c4 * 4;

  for (int cc = 0; cc < 6; ++cc) {
    const float* pl = xb + (size_t)(cc * 32 + cp * 2) * (HW * HW);
    float4 va = *(const float4*)pl;
    float4 vb = *(const float4*)(pl + HW * HW);
    float fa[4] = {va.x, va.y, va.z, va.w};
    float fb[4] = {vb.x, vb.y, vb.z, vb.w};
#pragma unroll
    for (int i = 0; i < 4; ++i) {
      int p = pS + i;
      unsigned int pk = bf16pack(fa[i], fb[i]);
      *(unsigned int*)((char*)Xs + (p * 128 + ((cp * 4) ^ ((p & 7) << 4)))) = pk;
    }
    part[cp * 2][gi]     = fa[0] + fa[1] + fa[2] + fa[3];
    part[cp * 2 + 1][gi] = fb[0] + fb[1] + fb[2] + fb[3];
    __syncthreads();

    // window-mean: 32 threads, ascending fixed-order sum (bit-identical order)
    if (t < 32) {
      float s = 0.0f;
#pragma unroll
      for (int rr = 0; rr < 8; ++rr) {
        s += part[t][rr * 2];
        s += part[t][rr * 2 + 1];
      }
      xmLds[cc * 32 + t] = s * (1.0f / 64.0f);
    }

    bf16x8 Bf[3];
#pragma unroll
    for (int dt = 0; dt < 3; ++dt)
      Bf[dt] = *(const bf16x8*)(wvt + (size_t)(dq * 48 + dt * 16 + col) * NC + cc * 32 + kg * 8);

#pragma unroll
    for (int pt = 0; pt < 4; ++pt) {
      int p = pt * 16 + col;
      bf16x8 Af = *(const bf16x8*)((const char*)Xs +
                    (p * 128 + ((kg * 16) ^ ((p & 7) << 4))));
      acc[pt][0] = __builtin_amdgcn_mfma_f32_16x16x32_bf16(Af, Bf[0], acc[pt][0], 0, 0, 0);
      acc[pt][1] = __builtin_amdgcn_mfma_f32_16x16x32_bf16(Af, Bf[1], acc[pt][1], 0, 0, 0);
      acc[pt][2] = __builtin_amdgcn_mfma_f32_16x16x32_bf16(Af, Bf[2], acc[pt][2], 0, 0, 0);
    }
    __syncthreads();
  }

  // ---- V tile store: wave-native packed layout, 256B coalesced wave stores ----
  unsigned int* vt = vtmp + (size_t)(b * NWIN + m) * 6144;
#pragma unroll
  for (int pt = 0; pt < 4; ++pt) {
#pragma unroll
    for (int dt = 0; dt < 3; ++dt) {
#pragma unroll
      for (int rrp = 0; rrp < 2; ++rrp) {
        unsigned int pk = bf16pack(acc[pt][dt][rrp * 2], acc[pt][dt][rrp * 2 + 1]);
        vt[(size_t)((((dq * 4 + pt) * 3 + dt) * 2 + rrp) * 64 + L)] = pk;
      }
    }
  }

  // ---- fused q/k projection: thread t owns cols t (q) and t+192 (k); f64, c ascending ----
  if (t < NDQ) {
    double aq = 0.0, ak = 0.0;
    for (int c = 0; c < NC; ++c) {
      double xc = (double)xmLds[c];
      aq += xc * (double)w[c * WCOL + t];
      ak += xc * (double)w[c * WCOL + NDQ + t];
    }
    qw[(size_t)(b * NWIN + m) * NC + t] = ((float)aq + bias[t]) * 0.0721687836487032f;
    kwT[(size_t)b * NC * NWIN + (size_t)t * NWIN + m] = (float)ak + bias[NDQ + t];
  }
}

// ---------------- K3: 8 logit rows per block, 1024 thr (16 waves), per-wave top-4 ----------------
__global__ __launch_bounds__(1024) void k3_topk(const float* __restrict__ qw,
                                                const float* __restrict__ kwT,
                                                int* __restrict__ topk) {
  int b = blockIdx.y, n0 = blockIdx.x * 8;
  int t = threadIdx.x;
  __shared__ float qs[8][NC];
  __shared__ float lg[8][NWIN];
  for (int l = t; l < 8 * NC; l += 1024) {
    int r = l / NC, c = l - r * NC;
    qs[r][c] = qw[(size_t)(b * NWIN + n0 + r) * NC + c];
  }
  __syncthreads();

  int col2 = (t & 511) * 2;
  int rg = (t >> 9) * 4;

  double acc[4][2];
#pragma unroll
  for (int r = 0; r < 4; ++r) { acc[r][0] = 0.0; acc[r][1] = 0.0; }

  const float* kb = kwT + (size_t)b * NC * NWIN;
#pragma unroll 2
  for (int c = 0; c < NC; ++c) {
    float2 kv = *(const float2*)(kb + (size_t)c * NWIN + col2);
    double k0 = (double)kv.x, k1 = (double)kv.y;
#pragma unroll
    for (int r = 0; r < 4; ++r) {
      double q = (double)qs[rg + r][c];
      acc[r][0] += q * k0;
      acc[r][1] += q * k1;
    }
  }
#pragma unroll
  for (int r = 0; r < 4; ++r) {
    lg[rg + r][col2]     = (float)acc[r][0];
    lg[rg + r][col2 + 1] = (float)acc[r][1];
  }
  __syncthreads();

  int wave = t >> 6, lane = t & 63;
  if (wave < 8) {
    int r = wave;
    float v4[4];
    int   i4[4];
#pragma unroll
    for (int j = 0; j < 4; ++j) { v4[j] = -INFINITY; i4[j] = 0x7fffffff; }
    for (int i = 0; i < 16; ++i) {
      int idx = i * 64 + lane;
      float v = lg[r][idx];
      if (v > v4[3] || (v == v4[3] && idx < i4[3])) {
        v4[3] = v; i4[3] = idx;
#pragma unroll
        for (int j = 3; j > 0; --j) {
          if (v4[j] > v4[j-1] || (v4[j] == v4[j-1] && i4[j] < i4[j-1])) {
            float tv = v4[j]; v4[j] = v4[j-1]; v4[j-1] = tv;
            int ti = i4[j]; i4[j] = i4[j-1]; i4[j-1] = ti;
          }
        }
      }
    }
    for (int m = 1; m < 64; m <<= 1) {
      float ov[4]; int oi[4];
#pragma unroll
      for (int j = 0; j < 4; ++j) { ov[j] = __shfl_xor(v4[j], m); oi[j] = __shfl_xor(i4[j], m); }
      float nv[4]; int ni[4];
      int ia = 0, ib = 0;
#pragma unroll
      for (int j = 0; j < 4; ++j) {
        bool ta = (v4[ia] > ov[ib]) || (v4[ia] == ov[ib] && i4[ia] < oi[ib]);
        if (ta) { nv[j] = v4[ia]; ni[j] = i4[ia]; ++ia; }
        else    { nv[j] = ov[ib]; ni[j] = oi[ib]; ++ib; }
      }
#pragma unroll
      for (int j = 0; j < 4; ++j) { v4[j] = nv[j]; i4[j] = ni[j]; }
    }
    if (lane == 0) {
      int n = n0 + r;
#pragma unroll
      for (int k = 0; k < 4; ++k)
        topk[(size_t)(b * NWIN + n) * 4 + k] = i4[k];
    }
  }
}

// ---------------- KB: gather + decode wave-native vtmp -> out[p][d] ----------------
__global__ __launch_bounds__(512) void kB_gather(const unsigned int* __restrict__ vtmp,
                                                 const int* __restrict__ topk,
                                                 float* __restrict__ out) {
  int id = blockIdx.x;            // 8192 = b*4096 + n*4 + k
  int b = id >> 12;
  int m = topk[id];
  const unsigned int* src = vtmp + (size_t)(b * NWIN + m) * 6144;
  float* dst = out + (size_t)id * (SHW * NC);
  int t = threadIdx.x;
#pragma unroll
  for (int i = 0; i < 3; ++i) {
    int u = i * 512 + t;          // 0..1535
    int j    = u & 15;
    int rem  = u >> 4;            // 0..95
    int rrp  = rem & 1;
    int rem2 = rem >> 1;
    int dt = rem2 % 3;
    int qp = rem2 / 3;
    int pt = qp & 3, dq = qp >> 2;
    uint4 v = *(const uint4*)(src + (size_t)rem * 64 + j * 4);
    int p0 = pt * 16 + (j >> 2) * 4 + rrp * 2;
    int d0 = dq * 48 + dt * 16 + (j & 3) * 4;
    float4 plo, phi;
    plo.x = __builtin_bit_cast(float, v.x << 16);
    phi.x = __builtin_bit_cast(float, v.x & 0xffff0000u);
    plo.y = __builtin_bit_cast(float, v.y << 16);
    phi.y = __builtin_bit_cast(float, v.y & 0xffff0000u);
    plo.z = __builtin_bit_cast(float, v.z << 16);
    phi.z = __builtin_bit_cast(float, v.z & 0xffff0000u);
    plo.w = __builtin_bit_cast(float, v.w << 16);
    phi.w = __builtin_bit_cast(float, v.w & 0xffff0000u);
    *(float4*)(dst + (size_t)p0 * NC + d0)       = plo;
    *(float4*)(dst + (size_t)(p0 + 1) * NC + d0) = phi;
  }
}

extern "C" void kernel_launch(void* const* d_in, const int* in_sizes, int n_in,
                              void* d_out, int out_size, void* d_ws, size_t ws_size,
                              hipStream_t stream) {
  const float* x    = (const float*)d_in[0];
  const float* w    = (const float*)d_in[1];
  const float* bias = (const float*)d_in[2];
  float* out = (float*)d_out;

  unsigned int* vtmp = (unsigned int*)d_ws;              // 2*1024*6144 dwords = 50 MB
  float* qw    = (float*)(vtmp + (size_t)12582912);      // 2*1024*192
  float* kwT   = qw + 393216;                            // 2*192*1024
  int*   topk  = (int*)(kwT + 393216);                   // 2*1024*4
  unsigned short* wvt = (unsigned short*)(topk + 8192);  // 192*192 bf16

  k0_wvt<<<144, 256, 0, stream>>>(w, wvt);
  kA_vgemm<<<dim3(1024, 2), 256, 0, stream>>>(x, wvt, w, bias, vtmp, qw, kwT);
  k3_topk<<<dim3(128, 2), 1024, 0, stream>>>(qw, kwT, topk);
  kB_gather<<<8192, 512, 0, stream>>>(vtmp, topk, out);
}

// Round 17
// 235.313 us; speedup vs baseline: 1.0532x; 1.0532x over previous
//
#include <hip/hip_runtime.h>
#include <hip/hip_bf16.h>
#include <math.h>

// x: (2, 192, 256, 256) f32 ; w_qkv: (192, 576) ; b_qkv: (576,)
// windows: 32x32 = 1024 per batch, 8x8=64 pixels each
// out: (2, 1024, 4, 64, 192) f32
#define NB   2
#define NC   192
#define HW   256
#define NWIN 1024
#define SHW  64
#define NDQ  192
#define WCOL 576

typedef short bf16x8 __attribute__((ext_vector_type(8)));
typedef float f32x4  __attribute__((ext_vector_type(4)));

__device__ inline unsigned int bf16pack(float a, float b) {
  unsigned int ua = __builtin_bit_cast(unsigned int, a);
  ua += 0x7fffu + ((ua >> 16) & 1u);
  unsigned int ub = __builtin_bit_cast(unsigned int, b);
  ub += 0x7fffu + ((ub >> 16) & 1u);
  return (ua >> 16) | (ub & 0xffff0000u);
}

__device__ inline unsigned short bf16r(float a) {
  unsigned int ua = __builtin_bit_cast(unsigned int, a);
  ua += 0x7fffu + ((ua >> 16) & 1u);
  return (unsigned short)(ua >> 16);
}

// ---------------- K0: precompute WvT bf16 [d][c] ----------------
__global__ __launch_bounds__(256) void k0_wvt(const float* __restrict__ w,
                                              unsigned short* __restrict__ wvt) {
  int id = blockIdx.x * 256 + threadIdx.x;   // 192*192 = 36864
  int d = id / NC, c = id - d * NC;
  wvt[d * NC + c] = bf16r(w[c * WCOL + 2 * NDQ + d]);
}

// ---------------- KA: 4 windows/block, 1024 thr; double-buffered staging ----------------
// vtmp layout per window (6144 dwords): [((dq*4+pt)*3+dt)*2+rrp][lane];
// dword = pack(bf16(p=pt*16+kg*4+2rrp), bf16(p+1)) at d = dq*48+dt*16+col, lane=kg*16+col.
__global__ __launch_bounds__(1024) void kA_vgemm(const float* __restrict__ x,
                                                 const unsigned short* __restrict__ wvt,
                                                 const float* __restrict__ w,
                                                 const float* __restrict__ bias,
                                                 unsigned int* __restrict__ vtmp,
                                                 float* __restrict__ qw,
                                                 float* __restrict__ kwT) {
  int b = blockIdx.y, g = blockIdx.x;   // g in [0,256)
  int m0 = g * 4;
  int wh = m0 >> 5, ww0 = m0 & 31;
  int t = threadIdx.x;

  __shared__ unsigned short Xs[2][16384];  // 64 KB double-buffered
  __shared__ float part[2][32][65];        // padded, double-buffered
  __shared__ float xmLds[4][NC];           // 3 KB

  int L = t & 63, wv = t >> 6;
  int win = wv >> 2, dq = wv & 3;
  int col = L & 15, kg = L >> 4;

  f32x4 acc[4][3];
#pragma unroll
  for (int dt = 0; dt < 3; ++dt) {
    float bv = bias[2 * NDQ + dq * 48 + dt * 16 + col];
    f32x4 bi = {bv, bv, bv, bv};
#pragma unroll
    for (int pt = 0; pt < 4; ++pt) acc[pt][dt] = bi;
  }

  int cp = t & 15, gi = t >> 4;
  int r = gi >> 3, w4 = gi & 7;
  int winS = w4 >> 1;
  int pS = r * 8 + (w4 & 1) * 4;
  const float* xb = x + (size_t)(b * NC) * (HW * HW) + (size_t)(wh * 8 + r) * HW + ww0 * 8 + w4 * 4;

  int rw = (t >> 5) & 3, rc = t & 31;

  // preload chunk 0
  float4 va, vb;
  {
    const float* pl = xb + (size_t)(cp * 2) * (HW * HW);
    va = *(const float4*)pl;
    vb = *(const float4*)(pl + HW * HW);
  }

  for (int cc = 0; cc < 6; ++cc) {
    int buf = cc & 1;
    // ---- write phase (from registers) ----
    float fa[4] = {va.x, va.y, va.z, va.w};
    float fb[4] = {vb.x, vb.y, vb.z, vb.w};
#pragma unroll
    for (int i = 0; i < 4; ++i) {
      int p = pS + i;
      unsigned int pk = bf16pack(fa[i], fb[i]);
      *(unsigned int*)((char*)Xs[buf] + (winS * 8192 + p * 128 + ((cp * 4) ^ ((p & 7) << 4)))) = pk;
    }
    part[buf][cp * 2][gi]     = fa[0] + fa[1] + fa[2] + fa[3];
    part[buf][cp * 2 + 1][gi] = fb[0] + fb[1] + fb[2] + fb[3];
    __syncthreads();   // single barrier per chunk (dbuf protects WAR)

    // ---- issue next chunk's loads (latency hides under reduce+MFMA) ----
    float4 nva, nvb;
    if (cc < 5) {
      const float* pl = xb + (size_t)((cc + 1) * 32 + cp * 2) * (HW * HW);
      nva = *(const float4*)pl;
      nvb = *(const float4*)(pl + HW * HW);
    }

    // ---- window-mean reduce (deterministic fixed order) ----
    if (t < 128) {
      float s = 0.0f;
#pragma unroll
      for (int rr = 0; rr < 8; ++rr) {
        s += part[buf][rc][rr * 8 + 2 * rw];
        s += part[buf][rc][rr * 8 + 2 * rw + 1];
      }
      xmLds[rw][cc * 32 + rc] = s * (1.0f / 64.0f);
    }

    // ---- MFMA on current buffer ----
    bf16x8 Bf[3];
#pragma unroll
    for (int dt = 0; dt < 3; ++dt)
      Bf[dt] = *(const bf16x8*)(wvt + (size_t)(dq * 48 + dt * 16 + col) * NC + cc * 32 + kg * 8);

#pragma unroll
    for (int pt = 0; pt < 4; ++pt) {
      int p = pt * 16 + col;
      bf16x8 Af = *(const bf16x8*)((const char*)Xs[buf] +
                    (win * 8192 + p * 128 + ((kg * 16) ^ ((p & 7) << 4))));
      acc[pt][0] = __builtin_amdgcn_mfma_f32_16x16x32_bf16(Af, Bf[0], acc[pt][0], 0, 0, 0);
      acc[pt][1] = __builtin_amdgcn_mfma_f32_16x16x32_bf16(Af, Bf[1], acc[pt][1], 0, 0, 0);
      acc[pt][2] = __builtin_amdgcn_mfma_f32_16x16x32_bf16(Af, Bf[2], acc[pt][2], 0, 0, 0);
    }

    va = nva; vb = nvb;
  }

  __syncthreads();   // xmLds complete before tail reads

  // ---- V tile store: wave-native packed layout, 256B coalesced wave stores ----
  unsigned int* vt = vtmp + (size_t)(b * NWIN + m0 + win) * 6144;
#pragma unroll
  for (int pt = 0; pt < 4; ++pt) {
#pragma unroll
    for (int dt = 0; dt < 3; ++dt) {
#pragma unroll
      for (int rrp = 0; rrp < 2; ++rrp) {
        unsigned int pk = bf16pack(acc[pt][dt][rrp * 2], acc[pt][dt][rrp * 2 + 1]);
        vt[(size_t)((((dq * 4 + pt) * 3 + dt) * 2 + rrp) * 64 + L)] = pk;
      }
    }
  }

  // ---- fused q/k projection (bit-identical to the former k2) ----
  for (int o = t; o < 1536; o += 1024) {
    int winq = o / 384;
    int d = o - winq * 384;
    const float* xr = xmLds[winq];
    double a = 0.0;
    for (int c = 0; c < NC; ++c)
      a += (double)xr[c] * (double)w[c * WCOL + d];
    float bv = bias[d];
    int n = m0 + winq;
    if (d < NDQ) {
      float qv = (float)a + bv;
      qw[(size_t)(b * NWIN + n) * NC + d] = qv * 0.0721687836487032f;
    } else {
      float kv = (float)a + bv;
      kwT[(size_t)b * NC * NWIN + (size_t)(d - NDQ) * NWIN + n] = kv;
    }
  }
}

// ---------------- K3: 8 logit rows per block, 1024 thr (16 waves), per-wave top-4 ----------------
__global__ __launch_bounds__(1024) void k3_topk(const float* __restrict__ qw,
                                                const float* __restrict__ kwT,
                                                int* __restrict__ topk) {
  int b = blockIdx.y, n0 = blockIdx.x * 8;
  int t = threadIdx.x;
  __shared__ float qs[8][NC];
  __shared__ float lg[8][NWIN];
  for (int l = t; l < 8 * NC; l += 1024) {
    int r = l / NC, c = l - r * NC;
    qs[r][c] = qw[(size_t)(b * NWIN + n0 + r) * NC + c];
  }
  __syncthreads();

  int col2 = (t & 511) * 2;
  int rg = (t >> 9) * 4;

  double acc[4][2];
#pragma unroll
  for (int r = 0; r < 4; ++r) { acc[r][0] = 0.0; acc[r][1] = 0.0; }

  const float* kb = kwT + (size_t)b * NC * NWIN;
#pragma unroll 2
  for (int c = 0; c < NC; ++c) {
    float2 kv = *(const float2*)(kb + (size_t)c * NWIN + col2);
    double k0 = (double)kv.x, k1 = (double)kv.y;
#pragma unroll
    for (int r = 0; r < 4; ++r) {
      double q = (double)qs[rg + r][c];
      acc[r][0] += q * k0;
      acc[r][1] += q * k1;
    }
  }
#pragma unroll
  for (int r = 0; r < 4; ++r) {
    lg[rg + r][col2]     = (float)acc[r][0];
    lg[rg + r][col2 + 1] = (float)acc[r][1];
  }
  __syncthreads();

  int wave = t >> 6, lane = t & 63;
  if (wave < 8) {
    int r = wave;
    float v4[4];
    int   i4[4];
#pragma unroll
    for (int j = 0; j < 4; ++j) { v4[j] = -INFINITY; i4[j] = 0x7fffffff; }
    for (int i = 0; i < 16; ++i) {
      int idx = i * 64 + lane;
      float v = lg[r][idx];
      if (v > v4[3] || (v == v4[3] && idx < i4[3])) {
        v4[3] = v; i4[3] = idx;
#pragma unroll
        for (int j = 3; j > 0; --j) {
          if (v4[j] > v4[j-1] || (v4[j] == v4[j-1] && i4[j] < i4[j-1])) {
            float tv = v4[j]; v4[j] = v4[j-1]; v4[j-1] = tv;
            int ti = i4[j]; i4[j] = i4[j-1]; i4[j-1] = ti;
          }
        }
      }
    }
    for (int m = 1; m < 64; m <<= 1) {
      float ov[4]; int oi[4];
#pragma unroll
      for (int j = 0; j < 4; ++j) { ov[j] = __shfl_xor(v4[j], m); oi[j] = __shfl_xor(i4[j], m); }
      float nv[4]; int ni[4];
      int ia = 0, ib = 0;
#pragma unroll
      for (int j = 0; j < 4; ++j) {
        bool ta = (v4[ia] > ov[ib]) || (v4[ia] == ov[ib] && i4[ia] < oi[ib]);
        if (ta) { nv[j] = v4[ia]; ni[j] = i4[ia]; ++ia; }
        else    { nv[j] = ov[ib]; ni[j] = oi[ib]; ++ib; }
      }
#pragma unroll
      for (int j = 0; j < 4; ++j) { v4[j] = nv[j]; i4[j] = ni[j]; }
    }
    if (lane == 0) {
      int n = n0 + r;
#pragma unroll
      for (int k = 0; k < 4; ++k)
        topk[(size_t)(b * NWIN + n) * 4 + k] = i4[k];
    }
  }
}

// ---------------- KB: gather + decode wave-native vtmp -> out[p][d] ----------------
__global__ __launch_bounds__(512) void kB_gather(const unsigned int* __restrict__ vtmp,
                                                 const int* __restrict__ topk,
                                                 float* __restrict__ out) {
  int id = blockIdx.x;            // 8192 = b*4096 + n*4 + k
  int b = id >> 12;
  int m = topk[id];
  const unsigned int* src = vtmp + (size_t)(b * NWIN + m) * 6144;
  float* dst = out + (size_t)id * (SHW * NC);
  int t = threadIdx.x;
#pragma unroll
  for (int i = 0; i < 3; ++i) {
    int u = i * 512 + t;          // 0..1535
    int j    = u & 15;
    int rem  = u >> 4;            // 0..95
    int rrp  = rem & 1;
    int rem2 = rem >> 1;
    int dt = rem2 % 3;
    int qp = rem2 / 3;
    int pt = qp & 3, dq = qp >> 2;
    uint4 v = *(const uint4*)(src + (size_t)rem * 64 + j * 4);
    int p0 = pt * 16 + (j >> 2) * 4 + rrp * 2;
    int d0 = dq * 48 + dt * 16 + (j & 3) * 4;
    float4 plo, phi;
    plo.x = __builtin_bit_cast(float, v.x << 16);
    phi.x = __builtin_bit_cast(float, v.x & 0xffff0000u);
    plo.y = __builtin_bit_cast(float, v.y << 16);
    phi.y = __builtin_bit_cast(float, v.y & 0xffff0000u);
    plo.z = __builtin_bit_cast(float, v.z << 16);
    phi.z = __builtin_bit_cast(float, v.z & 0xffff0000u);
    plo.w = __builtin_bit_cast(float, v.w << 16);
    phi.w = __builtin_bit_cast(float, v.w & 0xffff0000u);
    *(float4*)(dst + (size_t)p0 * NC + d0)       = plo;
    *(float4*)(dst + (size_t)(p0 + 1) * NC + d0) = phi;
  }
}

extern "C" void kernel_launch(void* const* d_in, const int* in_sizes, int n_in,
                              void* d_out, int out_size, void* d_ws, size_t ws_size,
                              hipStream_t stream) {
  const float* x    = (const float*)d_in[0];
  const float* w    = (const float*)d_in[1];
  const float* bias = (const float*)d_in[2];
  float* out = (float*)d_out;

  unsigned int* vtmp = (unsigned int*)d_ws;              // 2*1024*6144 dwords = 50 MB
  float* qw    = (float*)(vtmp + (size_t)12582912);      // 2*1024*192
  float* kwT   = qw + 393216;                            // 2*192*1024
  int*   topk  = (int*)(kwT + 393216);                   // 2*1024*4
  unsigned short* wvt = (unsigned short*)(topk + 8192);  // 192*192 bf16

  k0_wvt<<<144, 256, 0, stream>>>(w, wvt);
  kA_vgemm<<<dim3(256, 2), 1024, 0, stream>>>(x, wvt, w, bias, vtmp, qw, kwT);
  k3_topk<<<dim3(128, 2), 1024, 0, stream>>>(qw, kwT, topk);
  kB_gather<<<8192, 512, 0, stream>>>(vtmp, topk, out);
}

// Round 18
// 231.315 us; speedup vs baseline: 1.0714x; 1.0173x over previous
//
#include <hip/hip_runtime.h>
#include <hip/hip_bf16.h>
#include <math.h>

// x: (2, 192, 256, 256) f32 ; w_qkv: (192, 576) ; b_qkv: (576,)
// windows: 32x32 = 1024 per batch, 8x8=64 pixels each
// out: (2, 1024, 4, 64, 192) f32
#define NB   2
#define NC   192
#define HW   256
#define NWIN 1024
#define SHW  64
#define NDQ  192
#define WCOL 576

typedef short bf16x8 __attribute__((ext_vector_type(8)));
typedef float f32x4  __attribute__((ext_vector_type(4)));

__device__ inline unsigned int bf16pack(float a, float b) {
  unsigned int ua = __builtin_bit_cast(unsigned int, a);
  ua += 0x7fffu + ((ua >> 16) & 1u);
  unsigned int ub = __builtin_bit_cast(unsigned int, b);
  ub += 0x7fffu + ((ub >> 16) & 1u);
  return (ua >> 16) | (ub & 0xffff0000u);
}

__device__ inline unsigned short bf16r(float a) {
  unsigned int ua = __builtin_bit_cast(unsigned int, a);
  ua += 0x7fffu + ((ua >> 16) & 1u);
  return (unsigned short)(ua >> 16);
}

// ---------------- K0: precompute WvT bf16 [d][c] ----------------
__global__ __launch_bounds__(256) void k0_wvt(const float* __restrict__ w,
                                              unsigned short* __restrict__ wvt) {
  int id = blockIdx.x * 256 + threadIdx.x;   // 192*192 = 36864
  int d = id / NC, c = id - d * NC;
  wvt[d * NC + c] = bf16r(w[c * WCOL + 2 * NDQ + d]);
}

// ---------------- KA: 4 windows/block, 1024 thr; 2-stage staging (128B global segments) ----------------
// raw LDS layout: rawf[c*265 + r*33 + px], c 0..31, r 0..7, px 0..31 (padded strides: banks ok)
// vtmp layout per window (6144 dwords): [((dq*4+pt)*3+dt)*2+rrp][lane];
// dword = pack(bf16(p=pt*16+kg*4+2rrp), bf16(p+1)) at d = dq*48+dt*16+col, lane=kg*16+col.
__global__ __launch_bounds__(1024) void kA_vgemm(const float* __restrict__ x,
                                                 const unsigned short* __restrict__ wvt,
                                                 const float* __restrict__ w,
                                                 const float* __restrict__ bias,
                                                 unsigned int* __restrict__ vtmp,
                                                 float* __restrict__ qw,
                                                 float* __restrict__ kwT) {
  int b = blockIdx.y, g = blockIdx.x;   // g in [0,256)
  int m0 = g * 4;
  int wh = m0 >> 5, ww0 = m0 & 31;
  int t = threadIdx.x;

  __shared__ float rawf[8480];          // ~34 KB raw f32 chunk
  __shared__ unsigned short Xs[16384];  // 32 KB bf16 swizzled
  __shared__ float part[32][65];        // padded partials
  __shared__ float xmLds[4][NC];        // 3 KB

  int L = t & 63, wv = t >> 6;
  int win = wv >> 2, dq = wv & 3;
  int col = L & 15, kg = L >> 4;

  f32x4 acc[4][3];
#pragma unroll
  for (int dt = 0; dt < 3; ++dt) {
    float bv = bias[2 * NDQ + dq * 48 + dt * 16 + col];
    f32x4 bi = {bv, bv, bv, bv};
#pragma unroll
    for (int pt = 0; pt < 4; ++pt) acc[pt][dt] = bi;
  }

  // stage-1 identity: 128B-contiguous global segments
  int q1 = t & 3, seg = t >> 2;
  int sr = seg & 7, sc = seg >> 3;      // sc 0..31, sr 0..7
  const float* xs1 = x + (size_t)(b * NC + sc) * (HW * HW) + (size_t)(wh * 8 + sr) * HW + ww0 * 8 + q1 * 8;
  int rbase1 = sc * 265 + sr * 33 + q1 * 8;

  // stage-2 identity (identical data assignment to r13/r15 staging)
  int cp = t & 15, gi = t >> 4;
  int r = gi >> 3, w4 = gi & 7;
  int winS = w4 >> 1;
  int pS = r * 8 + (w4 & 1) * 4;
  int rb2 = (2 * cp) * 265 + r * 33 + w4 * 4;

  int rw = (t >> 5) & 3, rc = t & 31;

  // prologue: stage-1 chunk 0
  {
    float4 A = *(const float4*)xs1;
    float4 B = *(const float4*)(xs1 + 4);
    *(f32x4*)&rawf[rbase1]     = (f32x4){A.x, A.y, A.z, A.w};
    *(f32x4*)&rawf[rbase1 + 4] = (f32x4){B.x, B.y, B.z, B.w};
  }
  __syncthreads();

  for (int cc = 0; cc < 6; ++cc) {
    // ---- stage 2: raw LDS -> pack -> Xs + partials (identical to proven staging) ----
    f32x4 va = *(const f32x4*)&rawf[rb2];
    f32x4 vb = *(const f32x4*)&rawf[rb2 + 265];
    float fa[4] = {va.x, va.y, va.z, va.w};
    float fb[4] = {vb.x, vb.y, vb.z, vb.w};
#pragma unroll
    for (int i = 0; i < 4; ++i) {
      int p = pS + i;
      unsigned int pk = bf16pack(fa[i], fb[i]);
      *(unsigned int*)((char*)Xs + (winS * 8192 + p * 128 + ((cp * 4) ^ ((p & 7) << 4)))) = pk;
    }
    part[cp * 2][gi]     = fa[0] + fa[1] + fa[2] + fa[3];
    part[cp * 2 + 1][gi] = fb[0] + fb[1] + fb[2] + fb[3];
    __syncthreads();

    // ---- stage 1 for next chunk: 128B-contiguous loads into raw LDS ----
    if (cc < 5) {
      const float* ps = xs1 + (size_t)((cc + 1) * 32) * (HW * HW);
      float4 A = *(const float4*)ps;
      float4 B = *(const float4*)(ps + 4);
      *(f32x4*)&rawf[rbase1]     = (f32x4){A.x, A.y, A.z, A.w};
      *(f32x4*)&rawf[rbase1 + 4] = (f32x4){B.x, B.y, B.z, B.w};
    }

    // ---- window-mean reduce (deterministic fixed order, identical) ----
    if (t < 128) {
      float s = 0.0f;
#pragma unroll
      for (int rr = 0; rr < 8; ++rr) {
        s += part[rc][rr * 8 + 2 * rw];
        s += part[rc][rr * 8 + 2 * rw + 1];
      }
      xmLds[rw][cc * 32 + rc] = s * (1.0f / 64.0f);
    }

    // ---- MFMA on current Xs ----
    bf16x8 Bf[3];
#pragma unroll
    for (int dt = 0; dt < 3; ++dt)
      Bf[dt] = *(const bf16x8*)(wvt + (size_t)(dq * 48 + dt * 16 + col) * NC + cc * 32 + kg * 8);

#pragma unroll
    for (int pt = 0; pt < 4; ++pt) {
      int p = pt * 16 + col;
      bf16x8 Af = *(const bf16x8*)((const char*)Xs +
                    (win * 8192 + p * 128 + ((kg * 16) ^ ((p & 7) << 4))));
      acc[pt][0] = __builtin_amdgcn_mfma_f32_16x16x32_bf16(Af, Bf[0], acc[pt][0], 0, 0, 0);
      acc[pt][1] = __builtin_amdgcn_mfma_f32_16x16x32_bf16(Af, Bf[1], acc[pt][1], 0, 0, 0);
      acc[pt][2] = __builtin_amdgcn_mfma_f32_16x16x32_bf16(Af, Bf[2], acc[pt][2], 0, 0, 0);
    }
    __syncthreads();
  }

  // ---- V tile store: wave-native packed layout, 256B coalesced wave stores ----
  unsigned int* vt = vtmp + (size_t)(b * NWIN + m0 + win) * 6144;
#pragma unroll
  for (int pt = 0; pt < 4; ++pt) {
#pragma unroll
    for (int dt = 0; dt < 3; ++dt) {
#pragma unroll
      for (int rrp = 0; rrp < 2; ++rrp) {
        unsigned int pk = bf16pack(acc[pt][dt][rrp * 2], acc[pt][dt][rrp * 2 + 1]);
        vt[(size_t)((((dq * 4 + pt) * 3 + dt) * 2 + rrp) * 64 + L)] = pk;
      }
    }
  }

  // ---- fused q/k projection (bit-identical to the former k2) ----
  for (int o = t; o < 1536; o += 1024) {
    int winq = o / 384;
    int d = o - winq * 384;
    const float* xr = xmLds[winq];
    double a = 0.0;
    for (int c = 0; c < NC; ++c)
      a += (double)xr[c] * (double)w[c * WCOL + d];
    float bv = bias[d];
    int n = m0 + winq;
    if (d < NDQ) {
      float qv = (float)a + bv;
      qw[(size_t)(b * NWIN + n) * NC + d] = qv * 0.0721687836487032f;
    } else {
      float kv = (float)a + bv;
      kwT[(size_t)b * NC * NWIN + (size_t)(d - NDQ) * NWIN + n] = kv;
    }
  }
}

// ---------------- K3: 8 logit rows per block, 1024 thr (16 waves), per-wave top-4 ----------------
__global__ __launch_bounds__(1024) void k3_topk(const float* __restrict__ qw,
                                                const float* __restrict__ kwT,
                                                int* __restrict__ topk) {
  int b = blockIdx.y, n0 = blockIdx.x * 8;
  int t = threadIdx.x;
  __shared__ float qs[8][NC];
  __shared__ float lg[8][NWIN];
  for (int l = t; l < 8 * NC; l += 1024) {
    int r = l / NC, c = l - r * NC;
    qs[r][c] = qw[(size_t)(b * NWIN + n0 + r) * NC + c];
  }
  __syncthreads();

  int col2 = (t & 511) * 2;
  int rg = (t >> 9) * 4;

  double acc[4][2];
#pragma unroll
  for (int r = 0; r < 4; ++r) { acc[r][0] = 0.0; acc[r][1] = 0.0; }

  const float* kb = kwT + (size_t)b * NC * NWIN;
#pragma unroll 2
  for (int c = 0; c < NC; ++c) {
    float2 kv = *(const float2*)(kb + (size_t)c * NWIN + col2);
    double k0 = (double)kv.x, k1 = (double)kv.y;
#pragma unroll
    for (int r = 0; r < 4; ++r) {
      double q = (double)qs[rg + r][c];
      acc[r][0] += q * k0;
      acc[r][1] += q * k1;
    }
  }
#pragma unroll
  for (int r = 0; r < 4; ++r) {
    lg[rg + r][col2]     = (float)acc[r][0];
    lg[rg + r][col2 + 1] = (float)acc[r][1];
  }
  __syncthreads();

  int wave = t >> 6, lane = t & 63;
  if (wave < 8) {
    int r = wave;
    float v4[4];
    int   i4[4];
#pragma unroll
    for (int j = 0; j < 4; ++j) { v4[j] = -INFINITY; i4[j] = 0x7fffffff; }
    for (int i = 0; i < 16; ++i) {
      int idx = i * 64 + lane;
      float v = lg[r][idx];
      if (v > v4[3] || (v == v4[3] && idx < i4[3])) {
        v4[3] = v; i4[3] = idx;
#pragma unroll
        for (int j = 3; j > 0; --j) {
          if (v4[j] > v4[j-1] || (v4[j] == v4[j-1] && i4[j] < i4[j-1])) {
            float tv = v4[j]; v4[j] = v4[j-1]; v4[j-1] = tv;
            int ti = i4[j]; i4[j] = i4[j-1]; i4[j-1] = ti;
          }
        }
      }
    }
    for (int m = 1; m < 64; m <<= 1) {
      float ov[4]; int oi[4];
#pragma unroll
      for (int j = 0; j < 4; ++j) { ov[j] = __shfl_xor(v4[j], m); oi[j] = __shfl_xor(i4[j], m); }
      float nv[4]; int ni[4];
      int ia = 0, ib = 0;
#pragma unroll
      for (int j = 0; j < 4; ++j) {
        bool ta = (v4[ia] > ov[ib]) || (v4[ia] == ov[ib] && i4[ia] < oi[ib]);
        if (ta) { nv[j] = v4[ia]; ni[j] = i4[ia]; ++ia; }
        else    { nv[j] = ov[ib]; ni[j] = oi[ib]; ++ib; }
      }
#pragma unroll
      for (int j = 0; j < 4; ++j) { v4[j] = nv[j]; i4[j] = ni[j]; }
    }
    if (lane == 0) {
      int n = n0 + r;
#pragma unroll
      for (int k = 0; k < 4; ++k)
        topk[(size_t)(b * NWIN + n) * 4 + k] = i4[k];
    }
  }
}

// ---------------- KB: gather + decode wave-native vtmp -> out[p][d] ----------------
__global__ __launch_bounds__(512) void kB_gather(const unsigned int* __restrict__ vtmp,
                                                 const int* __restrict__ topk,
                                                 float* __restrict__ out) {
  int id = blockIdx.x;            // 8192 = b*4096 + n*4 + k
  int b = id >> 12;
  int m = topk[id];
  const unsigned int* src = vtmp + (size_t)(b * NWIN + m) * 6144;
  float* dst = out + (size_t)id * (SHW * NC);
  int t = threadIdx.x;
#pragma unroll
  for (int i = 0; i < 3; ++i) {
    int u = i * 512 + t;          // 0..1535
    int j    = u & 15;
    int rem  = u >> 4;            // 0..95
    int rrp  = rem & 1;
    int rem2 = rem >> 1;
    int dt = rem2 % 3;
    int qp = rem2 / 3;
    int pt = qp & 3, dq = qp >> 2;
    uint4 v = *(const uint4*)(src + (size_t)rem * 64 + j * 4);
    int p0 = pt * 16 + (j >> 2) * 4 + rrp * 2;
    int d0 = dq * 48 + dt * 16 + (j & 3) * 4;
    float4 plo, phi;
    plo.x = __builtin_bit_cast(float, v.x << 16);
    phi.x = __builtin_bit_cast(float, v.x & 0xffff0000u);
    plo.y = __builtin_bit_cast(float, v.y << 16);
    phi.y = __builtin_bit_cast(float, v.y & 0xffff0000u);
    plo.z = __builtin_bit_cast(float, v.z << 16);
    phi.z = __builtin_bit_cast(float, v.z & 0xffff0000u);
    plo.w = __builtin_bit_cast(float, v.w << 16);
    phi.w = __builtin_bit_cast(float, v.w & 0xffff0000u);
    *(float4*)(dst + (size_t)p0 * NC + d0)       = plo;
    *(float4*)(dst + (size_t)(p0 + 1) * NC + d0) = phi;
  }
}

extern "C" void kernel_launch(void* const* d_in, const int* in_sizes, int n_in,
                              void* d_out, int out_size, void* d_ws, size_t ws_size,
                              hipStream_t stream) {
  const float* x    = (const float*)d_in[0];
  const float* w    = (const float*)d_in[1];
  const float* bias = (const float*)d_in[2];
  float* out = (float*)d_out;

  unsigned int* vtmp = (unsigned int*)d_ws;              // 2*1024*6144 dwords = 50 MB
  float* qw    = (float*)(vtmp + (size_t)12582912);      // 2*1024*192
  float* kwT   = qw + 393216;                            // 2*192*1024
  int*   topk  = (int*)(kwT + 393216);                   // 2*1024*4
  unsigned short* wvt = (unsigned short*)(topk + 8192);  // 192*192 bf16

  k0_wvt<<<144, 256, 0, stream>>>(w, wvt);
  kA_vgemm<<<dim3(256, 2), 1024, 0, stream>>>(x, wvt, w, bias, vtmp, qw, kwT);
  k3_topk<<<dim3(128, 2), 1024, 0, stream>>>(qw, kwT, topk);
  kB_gather<<<8192, 512, 0, stream>>>(vtmp, topk, out);
}